// Round 16
// baseline (189.765 us; speedup 1.0000x reference)
//
#include <hip/hip_runtime.h>
#include <hip/hip_bf16.h>
#include <cfloat>

#define V_ALL  6145      // 6144 words + 1 tail-target token
#define NTOK   6144
#define SPLIT_ 2048
#define NROW   128
#define DDIM   256
#define TEMP_  65.0f
#define C2     2.8853900817779268f   // 2*log2(e): tanh(x) = 1 - 2/(2^(C2*x)+1)

// workspace layout in floats
#define EW_OFF 0
#define EW_SZ  (V_ALL * DDIM)          // 1,573,120 floats (pre-scaled by C2)
#define HU_OFF (EW_OFF + EW_SZ)
#define HU_SZ  (NROW * DDIM)           // pre-scaled by C2 (includes b)
#define HS_OFF (HU_OFF + HU_SZ)        // hsum[128]
#define TS_OFF (HS_OFF + NROW)         // tsum[128]
#define KT_OFF (TS_OFF + NROW)         // ktarget[128]
#define KL_OFF (KT_OFF + NROW)         // ktail[128]

// ---------------- kernel 1: hUs[n][d] = C2*(sum_k h[n][k]*U[k][d] + b[d]) ----
// also zeroes the hsum/tsum accumulators (runs before k_dist on the stream).
__global__ __launch_bounds__(256) void k_hu(const float* __restrict__ h,
                                            const float* __restrict__ U,
                                            const float* __restrict__ b,
                                            float* __restrict__ hUs,
                                            float* __restrict__ hsum,
                                            float* __restrict__ tsum) {
    const int d = threadIdx.x;
    const int n = blockIdx.x;
    if (d == 0) hsum[n] = 0.f;
    if (d == 1) tsum[n] = 0.f;
    const float4* __restrict__ hr = (const float4*)(h + n * DDIM); // uniform
    float acc = b[d];
    #pragma unroll 8
    for (int k4 = 0; k4 < DDIM / 4; ++k4) {
        float4 hv = hr[k4];
        int k = k4 * 4;
        acc = fmaf(hv.x, U[(k + 0) * DDIM + d], acc);
        acc = fmaf(hv.y, U[(k + 1) * DDIM + d], acc);
        acc = fmaf(hv.z, U[(k + 2) * DDIM + d], acc);
        acc = fmaf(hv.w, U[(k + 3) * DDIM + d], acc);
    }
    hUs[n * DDIM + d] = C2 * acc;
}

// ---------------- kernel 2: EWs[v][d] = C2 * sum_k emb[v][k]*W[k][d] ---------
__global__ __launch_bounds__(256) void k_ew(const float* __restrict__ emb,
                                            const float* __restrict__ W,
                                            float* __restrict__ EWs) {
    const int d = threadIdx.x;
    const int v0 = blockIdx.x * 8;
    const float4* __restrict__ er[8];
    #pragma unroll
    for (int i = 0; i < 8; ++i) {
        int r = v0 + i;
        if (r > V_ALL - 1) r = V_ALL - 1;
        er[i] = (const float4*)(emb + r * DDIM);
    }
    float acc[8];
    #pragma unroll
    for (int i = 0; i < 8; ++i) acc[i] = 0.f;

    for (int k4 = 0; k4 < DDIM / 4; ++k4) {
        const int k = k4 * 4;
        const float w0 = W[(k + 0) * DDIM + d];
        const float w1 = W[(k + 1) * DDIM + d];
        const float w2 = W[(k + 2) * DDIM + d];
        const float w3 = W[(k + 3) * DDIM + d];
        #pragma unroll
        for (int i = 0; i < 8; ++i) {
            float4 e = er[i][k4];
            acc[i] = fmaf(e.x, w0, acc[i]);
            acc[i] = fmaf(e.y, w1, acc[i]);
            acc[i] = fmaf(e.z, w2, acc[i]);
            acc[i] = fmaf(e.w, w3, acc[i]);
        }
    }
    #pragma unroll
    for (int i = 0; i < 8; ++i) {
        int r = v0 + i;
        if (r <= V_ALL - 1) EWs[r * DDIM + d] = C2 * acc[i];
    }
}

// ---------------- kernel 3: fused dist + kernel + online LSE, LDS-free -------
// thread = (n-row, 16-dim slice): h/hU slices live in REGISTERS; EWs read
// straight from global (L1/L2 broadcast across the 16 lanes of a slice group).
// dist reduced across the 16 dq-lanes via shfl_xor; all lanes then redundantly
// accumulate exp(k-65) so lane dq==0 holds the chunk sum -> 1 atomic per n.
__global__ __launch_bounds__(256) void k_dist(const float* __restrict__ EWs,
                                              const float* __restrict__ hUs,
                                              const float* __restrict__ h,
                                              const int* __restrict__ targets,
                                              float* __restrict__ hsum,
                                              float* __restrict__ tsum,
                                              float* __restrict__ ktarget,
                                              float* __restrict__ ktail) {
    const int dq = threadIdx.x & 15;          // which 16-dim slice
    const int nl = threadIdx.x >> 4;          // 0..15
    const int n  = blockIdx.y * 16 + nl;
    const int v0 = blockIdx.x * 16;
    const int d0 = dq * 16;

    float4 hr[4], ar[4];
    #pragma unroll
    for (int j = 0; j < 4; ++j) {
        hr[j] = *(const float4*)&h  [n * DDIM + d0 + 4 * j];
        ar[j] = *(const float4*)&hUs[n * DDIM + d0 + 4 * j];
    }
    const int tgt = targets[n];

    float acc_ek = 0.f;
    #pragma unroll 4
    for (int vi = 0; vi < 16; ++vi) {
        const int vg = v0 + vi;
        const float* __restrict__ ep = &EWs[vg * DDIM + d0];
        float acc0 = 0.f, acc1 = 0.f;
        #pragma unroll
        for (int j = 0; j < 4; ++j) {
            float4 e  = *(const float4*)(ep + 4 * j);
            float4 a  = ar[j];
            float4 hh = hr[j];
            // arg pre-scaled by C2: tanh = 1 - 2*rcp(2^arg + 1)
            { float E = __builtin_amdgcn_exp2f(e.x + a.x);
              float t = fmaf(-2.f, __builtin_amdgcn_rcpf(E + 1.f), 1.f);
              float df = hh.x - t; acc0 = fmaf(df, df, acc0); }
            { float E = __builtin_amdgcn_exp2f(e.y + a.y);
              float t = fmaf(-2.f, __builtin_amdgcn_rcpf(E + 1.f), 1.f);
              float df = hh.y - t; acc1 = fmaf(df, df, acc1); }
            { float E = __builtin_amdgcn_exp2f(e.z + a.z);
              float t = fmaf(-2.f, __builtin_amdgcn_rcpf(E + 1.f), 1.f);
              float df = hh.z - t; acc0 = fmaf(df, df, acc0); }
            { float E = __builtin_amdgcn_exp2f(e.w + a.w);
              float t = fmaf(-2.f, __builtin_amdgcn_rcpf(E + 1.f), 1.f);
              float df = hh.w - t; acc1 = fmaf(df, df, acc1); }
        }
        float dist = acc0 + acc1;
        dist += __shfl_xor(dist, 1, 16);
        dist += __shfl_xor(dist, 2, 16);
        dist += __shfl_xor(dist, 4, 16);
        dist += __shfl_xor(dist, 8, 16);
        const float kk = TEMP_ / (1.f + dist);    // exact div (matches ref path)
        float ek = __expf(kk - 65.f);             // in [e^-65, 1]
        if (vg > NTOK) ek = 0.f;                  // mask pad rows of chunk 384
        acc_ek += ek;                             // identical in all 16 lanes
        if (dq == 0) {
            if (vg == tgt)  ktarget[n] = kk;
            if (vg == NTOK) ktail[n]   = kk;
        }
    }
    // chunk is region-uniform: boundaries 2048/6144 are multiples of 16;
    // chunk v0==6144 holds only the tail-target token, which belongs to head.
    const bool is_head = (v0 < SPLIT_) || (v0 >= NTOK);
    if (dq == 0) atomicAdd(is_head ? &hsum[n] : &tsum[n], acc_ek);
}

// ---------------- kernel 4: per-row loss + mean ------------------------------
__global__ __launch_bounds__(128) void k_loss(const float* __restrict__ hsum,
                                              const float* __restrict__ tsum,
                                              const float* __restrict__ ktarget,
                                              const float* __restrict__ ktail,
                                              const int* __restrict__ targets,
                                              float* __restrict__ out) {
    const int n = threadIdx.x;
    const float logZh = 65.f + logf(hsum[n]);
    const int t = targets[n];
    float loss;
    if (t < SPLIT_) loss = logZh - ktarget[n];
    else            loss = logZh + 65.f + logf(tsum[n]) - ktail[n] - ktarget[n];

    #pragma unroll
    for (int o = 32; o; o >>= 1) loss += __shfl_down(loss, o);
    __shared__ float s[2];
    if ((n & 63) == 0) s[n >> 6] = loss;
    __syncthreads();
    if (n == 0) out[0] = (s[0] + s[1]) / (float)NROW;
}

extern "C" void kernel_launch(void* const* d_in, const int* in_sizes, int n_in,
                              void* d_out, int out_size, void* d_ws, size_t ws_size,
                              hipStream_t stream) {
    const float* h       = (const float*)d_in[0];
    const int*   targets = (const int*)  d_in[1];
    const float* emb     = (const float*)d_in[2];
    const float* W       = (const float*)d_in[3];
    const float* U       = (const float*)d_in[4];
    const float* b       = (const float*)d_in[5];

    float* ws  = (float*)d_ws;
    float* EWs = ws + EW_OFF;
    float* hUs = ws + HU_OFF;
    float* hs  = ws + HS_OFF;
    float* ts  = ws + TS_OFF;
    float* kt  = ws + KT_OFF;
    float* kl  = ws + KL_OFF;

    k_hu  <<<dim3(NROW),   dim3(256), 0, stream>>>(h, U, b, hUs, hs, ts);
    k_ew  <<<dim3(769),    dim3(256), 0, stream>>>(emb, W, EWs);           // ceil(6145/8)
    k_dist<<<dim3(385, 8), dim3(256), 0, stream>>>(EWs, hUs, h, targets,
                                                   hs, ts, kt, kl);        // 16-v chunks x 16-n
    k_loss<<<dim3(1),      dim3(128), 0, stream>>>(hs, ts, kt, kl, targets,
                                                   (float*)d_out);
}